// Round 3
// baseline (45.355 us; speedup 1.0000x reference)
//
#include <hip/hip_runtime.h>

// EntangleComplex: out_real = x_real * diag, out_imag = x_imag * diag
// diag[j] = (-1)^(number of cyclically-adjacent set bit pairs in j), j in [0,4096)
//
// Memory-bound sign flip. Non-temporal (nt) stores: the 128 MiB output stream
// bypasses L2/L3 -> the 128 MiB of read-only inputs stay resident in the
// 256 MiB Infinity Cache across graph replays; kernel becomes write-bound.
// Note: __builtin_nontemporal_store needs a NATIVE clang vector type, not
// HIP_vector_type -> use ext_vector_type(4) float.

#define NQ    12
#define DIM   4096          // 2^12
#define BATCH 4096
#define NELEM (BATCH * DIM) // 16,777,216 per array

typedef float vfloat4 __attribute__((ext_vector_type(4)));

__device__ __forceinline__ unsigned parity_sign_bit(unsigned j) {
    // bit i of k = bit (i+1)%12 of j  (cyclic rotate over 12 bits)
    unsigned k = (j >> 1) | ((j & 1u) << 11);
    return (__popc(j & k) & 1u) << 31;   // 0x80000000 if parity odd, else 0
}

__global__ __launch_bounds__(256) void entangle_sign_kernel(
    const vfloat4* __restrict__ xr,
    const vfloat4* __restrict__ xi,
    vfloat4* __restrict__ outr,
    vfloat4* __restrict__ outi,
    int nvec)
{
    const int stride = gridDim.x * blockDim.x;
    for (int v = blockIdx.x * blockDim.x + threadIdx.x; v < nvec; v += stride) {
        const unsigned j0 = ((unsigned)v * 4u) & (DIM - 1u);

        const unsigned s0 = parity_sign_bit(j0 + 0u);
        const unsigned s1 = parity_sign_bit(j0 + 1u);
        const unsigned s2 = parity_sign_bit(j0 + 2u);
        const unsigned s3 = parity_sign_bit(j0 + 3u);

        vfloat4 r = xr[v];   // regular loads: keep inputs L3-resident
        vfloat4 m = xi[v];

        vfloat4 ro, mo;
        ro.x = __uint_as_float(__float_as_uint(r.x) ^ s0);
        ro.y = __uint_as_float(__float_as_uint(r.y) ^ s1);
        ro.z = __uint_as_float(__float_as_uint(r.z) ^ s2);
        ro.w = __uint_as_float(__float_as_uint(r.w) ^ s3);
        mo.x = __uint_as_float(__float_as_uint(m.x) ^ s0);
        mo.y = __uint_as_float(__float_as_uint(m.y) ^ s1);
        mo.z = __uint_as_float(__float_as_uint(m.z) ^ s2);
        mo.w = __uint_as_float(__float_as_uint(m.w) ^ s3);

        // Non-temporal stores: bypass L2/L3, stream straight to HBM.
        __builtin_nontemporal_store(ro, &outr[v]);
        __builtin_nontemporal_store(mo, &outi[v]);
    }
}

extern "C" void kernel_launch(void* const* d_in, const int* in_sizes, int n_in,
                              void* d_out, int out_size, void* d_ws, size_t ws_size,
                              hipStream_t stream) {
    (void)in_sizes; (void)n_in; (void)d_ws; (void)ws_size; (void)out_size;

    const vfloat4* xr = (const vfloat4*)d_in[0];   // x_real [BATCH, DIM] fp32
    const vfloat4* xi = (const vfloat4*)d_in[1];   // x_imag [BATCH, DIM] fp32
    // d_in[2] = op [DIM, DIM] — diagonal, sign computed on-device, never read.

    float* out = (float*)d_out;
    vfloat4* outr = (vfloat4*)out;                    // output 0: real
    vfloat4* outi = (vfloat4*)(out + (size_t)NELEM);  // output 1: imag

    const int nvec = NELEM / 4;                       // 4,194,304 float4s per array
    const int block = 256;
    const int grid = 2048;                            // 8 blocks/CU, grid-stride x8

    entangle_sign_kernel<<<grid, block, 0, stream>>>(xr, xi, outr, outi, nvec);
}